// Round 1
// baseline (123.408 us; speedup 1.0000x reference)
//
#include <hip/hip_runtime.h>
#include <math.h>

// Problem constants (bert-base shapes from the reference)
#define L_  64
#define D_  768
#define B_  32
#define OD_ 1536   // 2*D
#define NW  8      // waves per block in pooled_kernel
#define NT  512    // threads per block in pooled_kernel (NW*64)

__device__ __forceinline__ float wsum(float v) {
#pragma unroll
    for (int off = 32; off > 0; off >>= 1) v += __shfl_xor(v, off, 64);
    return v;
}
__device__ __forceinline__ float wmaxr(float v) {
#pragma unroll
    for (int off = 32; off > 0; off >>= 1) v = fmaxf(v, __shfl_xor(v, off, 64));
    return v;
}
__device__ __forceinline__ int wsumi(int v) {
#pragma unroll
    for (int off = 32; off > 0; off >>= 1) v += __shfl_xor(v, off, 64);
    return v;
}

// One block per batch. Computes pooled[b, 0:768] without materializing the
// (4096, 768) pairwise-difference matrix, using the separability
//   We_[i,j] = s1[i] - s2[j],  pooled = sum_i rs[i]*a1[1+i] - sum_j cs[j]*a2[1+j]
__global__ __launch_bounds__(NT) void pooled_kernel(
    const float* __restrict__ a1, const float* __restrict__ a2,
    const int* __restrict__ m1, const int* __restrict__ m2,
    const float* __restrict__ we, float* __restrict__ pooled)
{
    const int b    = blockIdx.x;
    const int t    = threadIdx.x;
    const int lane = t & 63;
    const int wave = t >> 6;

    __shared__ float s1[L_], s2[L_];
    __shared__ float rowsum[L_], colsum[L_];
    __shared__ float colpart[NW][L_];
    __shared__ float wm[NW];
    __shared__ float sZ;
    __shared__ int   sl1, sl2;

    // content lengths: l = sum(mask) - 2
    if (wave == 0) {
        int s = wsumi(m1[b * L_ + lane]);
        if (lane == 0) sl1 = s - 2;
    } else if (wave == 1) {
        int s = wsumi(m2[b * L_ + lane]);
        if (lane == 0) sl2 = s - 2;
    }
    if (t < L_) rowsum[t] = 0.f;

    // we_w held in registers: 768 = 64 lanes * 12
    float wv[12];
#pragma unroll
    for (int k = 0; k < 12; k++) wv[k] = we[lane + 64 * k];

    __syncthreads();
    const int l1 = sl1, l2 = sl2;   // each in [8, 62]

    // s1[i] = dot(a1[b,1+i,:], we), s2[j] = dot(a2[b,1+j,:], we)
    // 128 row-dots spread across NW waves; rows beyond length -> 0 (unused)
    for (int r = wave; r < 2 * L_; r += NW) {
        const int which = r >> 6;           // 0 -> a1, 1 -> a2
        const int i     = r & 63;
        const int len   = which ? l2 : l1;
        float val = 0.f;
        if (i < len) {                       // wave-uniform branch
            const float* row = (which ? a2 : a1) + ((size_t)b * L_ + 1 + i) * D_;
            float acc = 0.f;
#pragma unroll
            for (int k = 0; k < 12; k++) acc = fmaf(row[lane + 64 * k], wv[k], acc);
            val = wsum(acc);
        }
        if (lane == 0) { if (which) s2[i] = val; else s1[i] = val; }
    }
    __syncthreads();

    // softmax over the l1 x l2 grid of v = s1[i]-s2[j], with the reference's
    // |v|<1e-7 -> -1e7 mask. Invalid region (kk >= l1*l2) has We_=0 -> -1e7
    // -> exp underflows to exactly 0 in fp32, so it is dropped.
    const float s2v = s2[lane];
    const bool  jok = (lane < l2);

    float lm = -1e30f;
    for (int i = wave; i < l1; i += NW) {
        float v = s1[i] - s2v;
        if (jok && fabsf(v) >= 1e-7f) lm = fmaxf(lm, v);
    }
    lm = wmaxr(lm);
    if (lane == 0) wm[wave] = lm;
    __syncthreads();
    float m = wm[0];
#pragma unroll
    for (int w = 1; w < NW; w++) m = fmaxf(m, wm[w]);

    // row/col marginals of exp(v - m)
    float colacc = 0.f;
    for (int i = wave; i < l1; i += NW) {
        float v = s1[i] - s2v;
        float e = (jok && fabsf(v) >= 1e-7f) ? __expf(v - m) : 0.f;
        float rs = wsum(e);
        if (lane == 0) rowsum[i] = rs;
        colacc += e;
    }
    colpart[wave][lane] = colacc;
    __syncthreads();

    if (wave == 0) {
        float c = 0.f;
#pragma unroll
        for (int w = 0; w < NW; w++) c += colpart[w][lane];
        colsum[lane] = c;                    // 0 for lane >= l2 automatically
        float Z = wsum(c);
        if (lane == 0) sZ = Z;
    }
    __syncthreads();
    const float invZ = 1.0f / sZ;

    // pooled[b,d] = (sum_i rs[i]*a1[b,1+i,d] - sum_j cs[j]*a2[b,1+j,d]) / Z
    for (int d = t; d < D_; d += NT) {
        float acc = 0.f;
        const float* p1 = a1 + ((size_t)b * L_ + 1) * D_ + d;
        for (int i = 0; i < l1; i++) acc = fmaf(rowsum[i], p1[(size_t)i * D_], acc);
        const float* p2 = a2 + ((size_t)b * L_ + 1) * D_ + d;
        for (int j = 0; j < l2; j++) acc = fmaf(-colsum[j], p2[(size_t)j * D_], acc);
        pooled[b * D_ + d] = acc * invZ;
    }
}

// out[b,o] = tanh(dot(fc_w[o,:], pooled[b,:]) + fc_b[o])
// block = 8 output rows x 32 batches; fc_w rows broadcast across 32 lanes.
__global__ __launch_bounds__(256) void fc_kernel(
    const float* __restrict__ pooled, const float* __restrict__ fc_w,
    const float* __restrict__ fc_b, float* __restrict__ out)
{
    const int t = threadIdx.x;
    const int b = t & 31;
    const int o = blockIdx.x * 8 + (t >> 5);

    const float4* wr = (const float4*)(fc_w + (size_t)o * D_);
    const float4* pr = (const float4*)(pooled + (size_t)b * D_);
    float acc0 = 0.f, acc1 = 0.f;
#pragma unroll 8
    for (int k = 0; k < D_ / 8; k++) {
        float4 w = wr[2 * k],     p = pr[2 * k];
        acc0 = fmaf(w.x, p.x, fmaf(w.y, p.y, fmaf(w.z, p.z, fmaf(w.w, p.w, acc0))));
        float4 w2 = wr[2 * k + 1], p2 = pr[2 * k + 1];
        acc1 = fmaf(w2.x, p2.x, fmaf(w2.y, p2.y, fmaf(w2.z, p2.z, fmaf(w2.w, p2.w, acc1))));
    }
    out[b * OD_ + o] = tanhf(acc0 + acc1 + fc_b[o]);
}

extern "C" void kernel_launch(void* const* d_in, const int* in_sizes, int n_in,
                              void* d_out, int out_size, void* d_ws, size_t ws_size,
                              hipStream_t stream) {
    const float* a1  = (const float*)d_in[0];   // (B, L, D) f32
    const float* a2  = (const float*)d_in[1];   // (B, L, D) f32
    const int*   m1  = (const int*)d_in[2];     // (B, L) i32
    const int*   m2  = (const int*)d_in[3];     // (B, L) i32
    const float* we  = (const float*)d_in[4];   // (1, D) f32
    const float* fcw = (const float*)d_in[5];   // (2D, D) f32
    const float* fcb = (const float*)d_in[6];   // (2D,) f32
    float*       out = (float*)d_out;           // (B, 2D) f32

    float* pooled = (float*)d_ws;               // B*D floats = 96 KiB scratch

    pooled_kernel<<<B_, NT, 0, stream>>>(a1, a2, m1, m2, we, pooled);
    fc_kernel<<<OD_ / 8, 256, 0, stream>>>(pooled, fcw, fcb, out);
}

// Round 2
// 122.517 us; speedup vs baseline: 1.0073x; 1.0073x over previous
//
#include <hip/hip_runtime.h>
#include <math.h>

// Problem constants (bert-base shapes from the reference)
#define L_  64
#define D_  768
#define B_  32
#define OD_ 1536   // 2*D

__device__ __forceinline__ float wsum(float v) {
#pragma unroll
    for (int off = 32; off > 0; off >>= 1) v += __shfl_xor(v, off, 64);
    return v;
}
__device__ __forceinline__ float wmaxr(float v) {
#pragma unroll
    for (int off = 32; off > 0; off >>= 1) v = fmaxf(v, __shfl_xor(v, off, 64));
    return v;
}
__device__ __forceinline__ int wsumi(int v) {
#pragma unroll
    for (int off = 32; off > 0; off >>= 1) v += __shfl_xor(v, off, 64);
    return v;
}

// ---------------------------------------------------------------------------
// K1: row scores. s1[b,i] = dot(a1[b,1+i,:], we), s2[b,j] = dot(a2[b,1+j,:], we)
// for ALL i,j in [0,63) (rows beyond the content length are garbage; K2 never
// reads them). One wave per row-dot -> 1024 blocks x 4 waves, fully parallel.
// ---------------------------------------------------------------------------
__global__ __launch_bounds__(256) void score_kernel(
    const float* __restrict__ a1, const float* __restrict__ a2,
    const float* __restrict__ we, float* __restrict__ s1ws,
    float* __restrict__ s2ws)
{
    const int lane = threadIdx.x & 63;
    const int wave = threadIdx.x >> 6;
    const int b    = blockIdx.x >> 5;
    const int slot = ((blockIdx.x & 31) << 2) + wave;   // [0,128)
    const int which = slot >> 6;                        // 0 -> a1, 1 -> a2
    const int i     = slot & 63;
    if (i >= 63) return;                                // row 1+i must be < 64

    const float* row = (which ? a2 : a1) + ((size_t)b * L_ + 1 + i) * D_ + lane;
    const float* w   = we + lane;
    float acc = 0.f;
#pragma unroll
    for (int k = 0; k < 12; k++) acc = fmaf(row[64 * k], w[64 * k], acc);
    acc = wsum(acc);
    if (lane == 0) (which ? s2ws : s1ws)[b * L_ + i] = acc;
}

// ---------------------------------------------------------------------------
// K2: softmax marginals (recomputed redundantly, tiny) + pooled chunk.
// Grid = B x 3; block = 256 threads = 4 waves; each block owns 256 dims of
// pooled[b,:]. Separability: We_[i,j] = s1[i]-s2[j];
//   pooled[b,d] = (sum_i rs[i]*a1[b,1+i,d] - sum_j cs[j]*a2[b,1+j,d]) / Z
// Invalid region (kk >= l1*l2) has We_=0 -> -1e7 -> exp == 0 in fp32: dropped.
// ---------------------------------------------------------------------------
#define NW2 4
__global__ __launch_bounds__(256) void pool_kernel(
    const float* __restrict__ a1, const float* __restrict__ a2,
    const int* __restrict__ m1, const int* __restrict__ m2,
    const float* __restrict__ s1ws, const float* __restrict__ s2ws,
    float* __restrict__ pooled)
{
    const int b     = blockIdx.x / 3;
    const int chunk = blockIdx.x % 3;
    const int t     = threadIdx.x;
    const int lane  = t & 63;
    const int wave  = t >> 6;

    __shared__ float rowsum[L_], colsum[L_];
    __shared__ float colpart[NW2][L_];
    __shared__ float wm[NW2];
    __shared__ float sZ;
    __shared__ int   sl1, sl2;

    if (wave == 0) {
        int s = wsumi(m1[b * L_ + lane]);
        if (lane == 0) sl1 = s - 2;
    } else if (wave == 1) {
        int s = wsumi(m2[b * L_ + lane]);
        if (lane == 0) sl2 = s - 2;
    }
    __syncthreads();
    const int l1 = sl1, l2 = sl2;            // each in [8, 62]

    const float s2v = s2ws[b * L_ + lane];   // garbage beyond l2; guarded below
    const bool  jok = (lane < l2);

    // pass 1: global max over valid, unmasked entries
    float lm = -1e30f;
    for (int i = wave; i < l1; i += NW2) {
        float v = s1ws[b * L_ + i] - s2v;
        if (jok && fabsf(v) >= 1e-7f) lm = fmaxf(lm, v);
    }
    lm = wmaxr(lm);
    if (lane == 0) wm[wave] = lm;
    __syncthreads();
    float m = wm[0];
#pragma unroll
    for (int w = 1; w < NW2; w++) m = fmaxf(m, wm[w]);

    // pass 2: row/col marginals of exp(v - m)
    float colacc = 0.f;
    for (int i = wave; i < l1; i += NW2) {
        float v = s1ws[b * L_ + i] - s2v;
        float e = (jok && fabsf(v) >= 1e-7f) ? __expf(v - m) : 0.f;
        float rs = wsum(e);
        if (lane == 0) rowsum[i] = rs;
        colacc += e;
    }
    colpart[wave][lane] = colacc;
    __syncthreads();
    if (wave == 0) {
        float c = 0.f;
#pragma unroll
        for (int w = 0; w < NW2; w++) c += colpart[w][lane];
        colsum[lane] = c;
        float Z = wsum(c);
        if (lane == 0) sZ = Z;
    }
    __syncthreads();
    const float invZ = 1.0f / sZ;

    // weighted row sums over this block's 256 dims (coalesced in d)
    const int d = chunk * 256 + t;
    const float* p1 = a1 + ((size_t)b * L_ + 1) * D_ + d;
    const float* p2 = a2 + ((size_t)b * L_ + 1) * D_ + d;
    float acc = 0.f;
    for (int i = 0; i < l1; i++) acc = fmaf(rowsum[i], p1[(size_t)i * D_], acc);
    for (int j = 0; j < l2; j++) acc = fmaf(-colsum[j], p2[(size_t)j * D_], acc);
    pooled[b * D_ + d] = acc * invZ;
}

// ---------------------------------------------------------------------------
// K3: out[b,o] = tanh(dot(fc_w[o,:], pooled[b,:]) + fc_b[o])
// block = 8 output rows x 32 batches; fc_w rows broadcast across 32 lanes.
// ---------------------------------------------------------------------------
__global__ __launch_bounds__(256) void fc_kernel(
    const float* __restrict__ pooled, const float* __restrict__ fc_w,
    const float* __restrict__ fc_b, float* __restrict__ out)
{
    const int t = threadIdx.x;
    const int b = t & 31;
    const int o = blockIdx.x * 8 + (t >> 5);

    const float4* wr = (const float4*)(fc_w + (size_t)o * D_);
    const float4* pr = (const float4*)(pooled + (size_t)b * D_);
    float acc0 = 0.f, acc1 = 0.f;
#pragma unroll 8
    for (int k = 0; k < D_ / 8; k++) {
        float4 w = wr[2 * k],      p = pr[2 * k];
        acc0 = fmaf(w.x, p.x, fmaf(w.y, p.y, fmaf(w.z, p.z, fmaf(w.w, p.w, acc0))));
        float4 w2 = wr[2 * k + 1], p2 = pr[2 * k + 1];
        acc1 = fmaf(w2.x, p2.x, fmaf(w2.y, p2.y, fmaf(w2.z, p2.z, fmaf(w2.w, p2.w, acc1))));
    }
    out[b * OD_ + o] = tanhf(acc0 + acc1 + fc_b[o]);
}

extern "C" void kernel_launch(void* const* d_in, const int* in_sizes, int n_in,
                              void* d_out, int out_size, void* d_ws, size_t ws_size,
                              hipStream_t stream) {
    const float* a1  = (const float*)d_in[0];   // (B, L, D) f32
    const float* a2  = (const float*)d_in[1];   // (B, L, D) f32
    const int*   m1  = (const int*)d_in[2];     // (B, L) i32
    const int*   m2  = (const int*)d_in[3];     // (B, L) i32
    const float* we  = (const float*)d_in[4];   // (1, D) f32
    const float* fcw = (const float*)d_in[5];   // (2D, D) f32
    const float* fcb = (const float*)d_in[6];   // (2D,) f32
    float*       out = (float*)d_out;           // (B, 2D) f32

    float* s1ws   = (float*)d_ws;               // B*L floats
    float* s2ws   = s1ws + B_ * L_;             // B*L floats
    float* pooled = s2ws + B_ * L_;             // B*D floats

    score_kernel<<<B_ * 32, 256, 0, stream>>>(a1, a2, we, s1ws, s2ws);
    pool_kernel<<<B_ * 3, 256, 0, stream>>>(a1, a2, m1, m2, s1ws, s2ws, pooled);
    fc_kernel<<<OD_ / 8, 256, 0, stream>>>(pooled, fcw, fcb, out);
}